// Round 1
// baseline (13.289 us; speedup 1.0000x reference)
//
#include <hip/hip_runtime.h>
#include <math.h>

#define DIMS 16
#define BATCH 32768

// W layout (flat, P=4845): [0]=const, [1..16]=deg1, [17..152]=deg2,
// [153..968]=deg3, [969..4844]=deg4, lex order (combinations_with_replacement).
__device__ constexpr int cnt2(int j){ return 16 - j; }                        // #(i1>=j) deg-2 tails
__device__ constexpr int cnt3(int j){ return (16 - j) * (17 - j) / 2; }       // #(i1<=i2) pairs from j
__device__ constexpr int cnt4(int j){ return (16 - j) * (17 - j) * (18 - j) / 6; }
__device__ constexpr int off2(int i0){ int s = 0; for (int j = 0; j < i0; ++j) s += cnt2(j); return s; }
__device__ constexpr int off3(int i0){ int s = 0; for (int j = 0; j < i0; ++j) s += cnt3(j); return s; }
__device__ constexpr int off4(int i0){ int s = 0; for (int j = 0; j < i0; ++j) s += cnt4(j); return s; }

// Fully-unrolled contribution of all monomials whose FIRST index is I0.
// After unrolling, every W index is a compile-time constant on a uniform
// pointer (-> s_load imm-offset) and every xv index is constant (-> VGPR).
template<int I0>
__device__ __forceinline__ void do_i0(const float* __restrict__ W,
                                      const float* __restrict__ xv,
                                      float& a1, float& a2, float& a3, float& a4)
{
    const float x0 = xv[I0];
    a1 = fmaf(W[1 + I0], x0, a1);
    int k2 = 17  + off2(I0);
    int k3 = 153 + off3(I0);
    int k4 = 969 + off4(I0);
    #pragma unroll
    for (int i1 = I0; i1 < DIMS; ++i1) {
        const float p2 = x0 * xv[i1];
        a2 = fmaf(W[k2++], p2, a2);
        #pragma unroll
        for (int i2 = i1; i2 < DIMS; ++i2) {
            const float p3 = p2 * xv[i2];
            a3 = fmaf(W[k3++], p3, a3);
            float s4 = 0.0f;
            #pragma unroll
            for (int i3 = i2; i3 < DIMS; ++i3)
                s4 = fmaf(W[k4++], xv[i3], s4);
            a4 = fmaf(p3, s4, a4);
        }
    }
}

template<int... Is>
__device__ __forceinline__ float role_partial(const float* __restrict__ W,
                                              const float* __restrict__ xv,
                                              float w1, float w2, float w3, float w4)
{
    float a1 = 0.f, a2 = 0.f, a3 = 0.f, a4 = 0.f;
    (do_i0<Is>(W, xv, a1, a2, a3, a4), ...);
    return fmaf(w1, a1, fmaf(w2, a2, fmaf(w3, a3, w4 * a4)));
}

// Block = 256 threads = 4 waves. Each block handles 64 samples (lane = sample).
// Wave w = role w: a balanced i0-partition of the triangular monomial nest.
// Role op counts: {0,6}=1663 {1,5,13,14,15}=1638 {2,4,11,12}=1677 {3,7,8,9,10}=1634.
__global__ __launch_bounds__(256, 2)
void poly_logreg_kernel(const float* __restrict__ x,
                        const float* __restrict__ W,
                        const float* __restrict__ b,
                        const float* __restrict__ M_raw,
                        float* __restrict__ out)
{
    const int lane = threadIdx.x & 63;
    const int wave = threadIdx.x >> 6;
    const int s    = (blockIdx.x << 6) + lane;

    // degree gates (scalar, tiny)
    const float M  = 3.0f / (1.0f + __expf(-M_raw[0])) + 1.0f;
    const float w1 = 1.0f / (1.0f + __expf(-10.0f * (M - 1.0f + 0.5f)));
    const float w2 = 1.0f / (1.0f + __expf(-10.0f * (M - 2.0f + 0.5f)));
    const float w3 = 1.0f / (1.0f + __expf(-10.0f * (M - 3.0f + 0.5f)));
    const float w4 = 1.0f / (1.0f + __expf(-10.0f * (M - 4.0f + 0.5f)));

    // load this sample's 16 x-values (64 B, 4x float4, stays in VGPRs)
    float xv[DIMS];
    const float4* xp = reinterpret_cast<const float4*>(x + (size_t)s * DIMS);
    #pragma unroll
    for (int q = 0; q < 4; ++q) {
        const float4 v = xp[q];
        xv[q * 4 + 0] = v.x; xv[q * 4 + 1] = v.y;
        xv[q * 4 + 2] = v.z; xv[q * 4 + 3] = v.w;
    }

    float partial;
    if (wave == 0)      partial = role_partial<0, 6>(W, xv, w1, w2, w3, w4);
    else if (wave == 1) partial = role_partial<1, 5, 13, 14, 15>(W, xv, w1, w2, w3, w4);
    else if (wave == 2) partial = role_partial<2, 4, 11, 12>(W, xv, w1, w2, w3, w4);
    else                partial = role_partial<3, 7, 8, 9, 10>(W, xv, w1, w2, w3, w4);

    __shared__ float part_lds[3][64];
    if (wave > 0) part_lds[wave - 1][lane] = partial;
    __syncthreads();

    if (wave == 0) {
        const float logit = W[0] + b[0] + partial
                          + part_lds[0][lane] + part_lds[1][lane] + part_lds[2][lane];
        out[s] = 1.0f / (1.0f + __expf(-logit));
    }
}

extern "C" void kernel_launch(void* const* d_in, const int* in_sizes, int n_in,
                              void* d_out, int out_size, void* d_ws, size_t ws_size,
                              hipStream_t stream)
{
    const float* x     = (const float*)d_in[0];
    const float* W     = (const float*)d_in[1];
    const float* b     = (const float*)d_in[2];
    const float* M_raw = (const float*)d_in[3];
    float* out = (float*)d_out;

    const int blocks = BATCH / 64;   // 512 blocks x 4 waves = 2048 waves = 2/SIMD
    poly_logreg_kernel<<<blocks, 256, 0, stream>>>(x, W, b, M_raw, out);
}

// Round 2
// 12.589 us; speedup vs baseline: 1.0556x; 1.0556x over previous
//
#include <hip/hip_runtime.h>
#include <utility>
#include <math.h>

#define DIMS  16
#define BATCH 32768
#define NPAIR 136
#define NROLE 8

// ---------- compile-time combinatorics (lex order = combinations_with_replacement) ----------
constexpr int pairlex(int i0, int i1) {           // index of pair (i0,i1), i0<=i1
    int s = 0;
    for (int j = 0; j < i0; ++j) s += (DIMS - j);
    return s + (i1 - i0);
}
constexpr int cnt3(int j) { return (DIMS - j) * (DIMS + 1 - j) / 2; }
constexpr int cnt4(int j) { return (DIMS - j) * (DIMS + 1 - j) * (DIMS + 2 - j) / 6; }
constexpr int off3(int i0) { int s = 0; for (int j = 0; j < i0; ++j) s += cnt3(j); return s; }
constexpr int off4(int i0) { int s = 0; for (int j = 0; j < i0; ++j) s += cnt4(j); return s; }

// W layout: [0]=const, [1..16]=deg1, [17..152]=deg2, [153..968]=deg3, [969..4844]=deg4
constexpr int w2idx(int i0, int i1) { return 1 + DIMS + pairlex(i0, i1); }
constexpr int w3base(int i0, int i1) {            // first deg-3 coeff with prefix (i0,i1)
    int s = off3(i0);
    for (int b = i0; b < i1; ++b) s += (DIMS - b);
    return 1 + DIMS + NPAIR + s;                  // 153 + ...
}
constexpr int w4base(int i0, int i1) {            // first deg-4 coeff with prefix (i0,i1)
    int s = off4(i0);
    for (int b = i0; b < i1; ++b) s += cnt3(b);
    return 1 + DIMS + NPAIR + 816 + s;            // 969 + ...
}
static_assert(pairlex(15, 15) == 135, "pairlex");
static_assert(off3(DIMS) == 816 && off4(DIMS) == 3876, "counts");
static_assert(w3base(15, 15) == 968, "w3 tail");
static_assert(w4base(15, 15) == 4844, "w4 tail");

// exact VALU-op cost of pair (i0,i1): depends only on i1
constexpr int costv(int v) { return (DIMS - v) + (DIMS + 1 - v) * (DIMS + 2 - v) / 2 + 3; }

// ---------- compile-time LPT partition of the 136 pairs into 8 balanced roles ----------
struct Plan { int role_of[NPAIR]; int d1_role; };
constexpr Plan make_plan() {
    Plan p{};
    long load[NROLE] = {};
    for (int v = 0; v < DIMS; ++v)            // costs are descending in v -> LPT order
        for (int i0 = 0; i0 <= v; ++i0) {
            int best = 0;
            for (int r = 1; r < NROLE; ++r) if (load[r] < load[best]) best = r;
            p.role_of[pairlex(i0, v)] = best;
            load[best] += costv(v);
        }
    int best = 0;
    for (int r = 1; r < NROLE; ++r) if (load[r] < load[best]) best = r;
    p.d1_role = best;                          // degree-1 terms go to the lightest role
    return p;
}
inline constexpr Plan PLAN = make_plan();

constexpr int pid_i0(int pid) {
    int i0 = 0, rem = pid;
    while (rem >= DIMS - i0) { rem -= DIMS - i0; ++i0; }
    return i0;
}
constexpr int pid_i1(int pid) {
    int i0 = 0, rem = pid;
    while (rem >= DIMS - i0) { rem -= DIMS - i0; ++i0; }
    return i0 + rem;
}

// ---------- static_for ----------
template<typename F, int... Is>
__device__ __forceinline__ void static_for_impl(F&& f, std::integer_sequence<int, Is...>) {
    (f(std::integral_constant<int, Is>{}), ...);
}
template<int N, typename F>
__device__ __forceinline__ void static_for(F&& f) {
    static_for_impl(static_cast<F&&>(f), std::make_integer_sequence<int, N>{});
}

// ---------- per-pair fully-unrolled body (6068-FMA scheme) ----------
// contribution of all monomials whose first two indices are (I0,I1):
//   deg2: W2 * p2
//   deg3: p2 * sum_{i2>=I1} W3[..] x_i2                  (suffix dot s3)
//   deg4: p2 * sum_{i2>=I1} x_i2 * sum_{i3>=i2} W4[..] x_i3   (suffix dots s4, chain t)
template<int I0, int I1>
__device__ __forceinline__ void do_pair(const float* __restrict__ W,
                                        const float* __restrict__ xv,
                                        float& a2, float& a3, float& a4)
{
    constexpr int KW2 = w2idx(I0, I1);
    constexpr int KW3 = w3base(I0, I1);
    constexpr int KW4 = w4base(I0, I1);

    const float p2 = xv[I0] * xv[I1];
    a2 = fmaf(W[KW2], p2, a2);

    float s3 = 0.f;
    #pragma unroll
    for (int i2 = I1; i2 < DIMS; ++i2)
        s3 = fmaf(W[KW3 + (i2 - I1)], xv[i2], s3);
    a3 = fmaf(p2, s3, a3);

    float t = 0.f;
    int k = KW4;                                 // folds to constants after unroll
    #pragma unroll
    for (int i2 = I1; i2 < DIMS; ++i2) {
        float s4 = 0.f;
        #pragma unroll
        for (int i3 = i2; i3 < DIMS; ++i3)
            s4 = fmaf(W[k++], xv[i3], s4);
        t = fmaf(xv[i2], s4, t);
    }
    a4 = fmaf(p2, t, a4);
}

template<int R>
__device__ __forceinline__ float role_body(const float* __restrict__ W,
                                           const float* __restrict__ xv,
                                           float w1, float w2, float w3, float w4)
{
    float a1 = 0.f, a2 = 0.f, a3 = 0.f, a4 = 0.f;
    static_for<NPAIR>([&](auto K) {
        constexpr int pid = decltype(K)::value;
        if constexpr (PLAN.role_of[pid] == R) {
            do_pair<pid_i0(pid), pid_i1(pid)>(W, xv, a2, a3, a4);
        }
    });
    if constexpr (R == PLAN.d1_role) {
        #pragma unroll
        for (int i = 0; i < DIMS; ++i)
            a1 = fmaf(W[1 + i], xv[i], a1);
    }
    return fmaf(w1, a1, fmaf(w2, a2, fmaf(w3, a3, w4 * a4)));
}

// Block = 512 threads = 8 role-waves over the same 64 samples (lane = sample).
// 512 blocks -> 2 blocks/CU -> 16 waves/CU = 4 waves/SIMD.
__global__ __launch_bounds__(512, 4)
void poly_logreg_kernel(const float* __restrict__ x,
                        const float* __restrict__ W,
                        const float* __restrict__ b,
                        const float* __restrict__ M_raw,
                        float* __restrict__ out)
{
    const int lane = threadIdx.x & 63;
    const int wave = threadIdx.x >> 6;           // 0..7 = role
    const int s    = (blockIdx.x << 6) + lane;

    // degree gates (uniform scalars)
    const float M  = 3.0f / (1.0f + __expf(-M_raw[0])) + 1.0f;
    const float w1 = 1.0f / (1.0f + __expf(-10.0f * (M - 0.5f)));
    const float w2 = 1.0f / (1.0f + __expf(-10.0f * (M - 1.5f)));
    const float w3 = 1.0f / (1.0f + __expf(-10.0f * (M - 2.5f)));
    const float w4 = 1.0f / (1.0f + __expf(-10.0f * (M - 3.5f)));

    // this sample's 16 x values -> VGPRs (compile-time indexed only)
    float xv[DIMS];
    const float4* xp = reinterpret_cast<const float4*>(x + (size_t)s * DIMS);
    #pragma unroll
    for (int q = 0; q < 4; ++q) {
        const float4 v = xp[q];
        xv[q * 4 + 0] = v.x; xv[q * 4 + 1] = v.y;
        xv[q * 4 + 2] = v.z; xv[q * 4 + 3] = v.w;
    }

    float partial;
    switch (wave) {
        case 0:  partial = role_body<0>(W, xv, w1, w2, w3, w4); break;
        case 1:  partial = role_body<1>(W, xv, w1, w2, w3, w4); break;
        case 2:  partial = role_body<2>(W, xv, w1, w2, w3, w4); break;
        case 3:  partial = role_body<3>(W, xv, w1, w2, w3, w4); break;
        case 4:  partial = role_body<4>(W, xv, w1, w2, w3, w4); break;
        case 5:  partial = role_body<5>(W, xv, w1, w2, w3, w4); break;
        case 6:  partial = role_body<6>(W, xv, w1, w2, w3, w4); break;
        default: partial = role_body<7>(W, xv, w1, w2, w3, w4); break;
    }

    __shared__ float red[NROLE - 1][64];
    if (wave) red[wave - 1][lane] = partial;
    __syncthreads();

    if (wave == 0) {
        float logit = W[0] + b[0] + partial;
        #pragma unroll
        for (int w = 0; w < NROLE - 1; ++w) logit += red[w][lane];
        out[s] = 1.0f / (1.0f + __expf(-logit));
    }
}

extern "C" void kernel_launch(void* const* d_in, const int* in_sizes, int n_in,
                              void* d_out, int out_size, void* d_ws, size_t ws_size,
                              hipStream_t stream)
{
    const float* x     = (const float*)d_in[0];
    const float* W     = (const float*)d_in[1];
    const float* b     = (const float*)d_in[2];
    const float* M_raw = (const float*)d_in[3];
    float* out = (float*)d_out;

    const int blocks = BATCH / 64;               // 512 blocks x 512 threads
    poly_logreg_kernel<<<blocks, 512, 0, stream>>>(x, W, b, M_raw, out);
}